// Round 1
// baseline (679.389 us; speedup 1.0000x reference)
//
#include <hip/hip_runtime.h>

#define HIDDEN 4096
#define INTER  11008
#define MTOK   128          // B*S = 8*16
#define NMERG  (2*INTER)    // 22016

typedef short  short8  __attribute__((ext_vector_type(8)));
typedef float  f32x16  __attribute__((ext_vector_type(16)));

// round-to-nearest-even fp32 -> bf16 bits
static __device__ __forceinline__ unsigned short f2bf_rne(float f) {
    unsigned u = __builtin_bit_cast(unsigned, f);
    u += 0x7FFFu + ((u >> 16) & 1u);
    return (unsigned short)(u >> 16);
}

// pack two fp32 into bf16x2 by truncation (exact for integer-valued weights)
static __device__ __forceinline__ int pk2(float lo, float hi) {
    return (int)__builtin_amdgcn_perm(__builtin_bit_cast(unsigned, hi),
                                      __builtin_bit_cast(unsigned, lo),
                                      0x07060302u);
}

// ---------------- x fp32 -> bf16 ----------------
__global__ void cvt_x_k(const float* __restrict__ x, unsigned short* __restrict__ xb) {
    int i = (blockIdx.x * 256 + threadIdx.x) * 4;
    float4 v = *(const float4*)(x + i);
    ushort4 o;
    o.x = f2bf_rne(v.x); o.y = f2bf_rne(v.y); o.z = f2bf_rne(v.z); o.w = f2bf_rne(v.w);
    *(ushort4*)(xb + i) = o;
}

// ---------------- fused dequant GEMM partial ----------------
// D_part[ks][m][n] = sum_{k in chunk ks} A[m][k] * B[n][k]
// A: bf16 [MTOK][K]; B rows: fp32 (integer-valued) [.][K]; n < nhalf -> B0 row n, else B1 row n-nhalf.
// block = 128 threads (2 waves); wave handles 32 n-cols x all 128 m (4 MFMA 32x32x16 acc).
__global__ __launch_bounds__(128) void gemm_part_k(
    const unsigned short* __restrict__ Abf,
    const float* __restrict__ B0, const float* __restrict__ B1, int nhalf,
    float* __restrict__ part, int K, int N, int kchunk)
{
    const int lane = threadIdx.x & 63;
    const int wave = threadIdx.x >> 6;
    const int n    = blockIdx.x * 64 + wave * 32 + (lane & 31);
    const int ks   = blockIdx.y;
    const int kq   = (lane >> 5) * 8;      // k sub-offset within 16-step

    const float* Brow = (n < nhalf) ? (B0 + (size_t)n * K)
                                    : (B1 + (size_t)(n - nhalf) * K);
    const int kbeg = ks * kchunk;
    const float* bp = Brow + kbeg + kq;
    const unsigned short* ap = Abf + (size_t)(lane & 31) * K + kbeg + kq;
    const size_t mstride = (size_t)32 * K;

    f32x16 acc[4];
#pragma unroll
    for (int t = 0; t < 4; ++t)
#pragma unroll
        for (int r = 0; r < 16; ++r) acc[t][r] = 0.f;

#pragma unroll 2
    for (int k = 0; k < kchunk; k += 16) {
        float4 b0 = *(const float4*)(bp);
        float4 b1 = *(const float4*)(bp + 4);
        int4 bi;
        bi.x = pk2(b0.x, b0.y); bi.y = pk2(b0.z, b0.w);
        bi.z = pk2(b1.x, b1.y); bi.w = pk2(b1.z, b1.w);
        short8 bf = __builtin_bit_cast(short8, bi);
        short8 a0 = *reinterpret_cast<const short8*>(ap);
        short8 a1 = *reinterpret_cast<const short8*>(ap + mstride);
        short8 a2 = *reinterpret_cast<const short8*>(ap + 2 * mstride);
        short8 a3 = *reinterpret_cast<const short8*>(ap + 3 * mstride);
        acc[0] = __builtin_amdgcn_mfma_f32_32x32x16_bf16(a0, bf, acc[0], 0, 0, 0);
        acc[1] = __builtin_amdgcn_mfma_f32_32x32x16_bf16(a1, bf, acc[1], 0, 0, 0);
        acc[2] = __builtin_amdgcn_mfma_f32_32x32x16_bf16(a2, bf, acc[2], 0, 0, 0);
        acc[3] = __builtin_amdgcn_mfma_f32_32x32x16_bf16(a3, bf, acc[3], 0, 0, 0);
        bp += 16; ap += 16;
    }

    // C/D layout (verified m74/m101): col(n)=lane&31, row(m)=(r&3)+8*(r>>2)+4*(lane>>5)
    float* outp = part + (size_t)ks * MTOK * (size_t)N;
#pragma unroll
    for (int t = 0; t < 4; ++t)
#pragma unroll
        for (int r = 0; r < 16; ++r) {
            int m = t * 32 + (r & 3) + 8 * (r >> 2) + 4 * (lane >> 5);
            outp[(size_t)m * N + n] = acc[t][r];
        }
}

// ---------------- combine K-split partials, scale, SwiGLU -> h bf16 ----------------
__global__ void swiglu_k(const float* __restrict__ y,   // [2][MTOK][NMERG]
                         const float* __restrict__ s1, const float* __restrict__ s3,
                         unsigned short* __restrict__ h) // [MTOK][INTER] bf16
{
    int i = blockIdx.x * 256 + threadIdx.x;      // over MTOK*INTER/4
    int m = i / (INTER / 4);
    int j = (i % (INTER / 4)) * 4;
    size_t r0 = (size_t)m * NMERG + j;
    size_t r1 = (size_t)(MTOK + m) * NMERG + j;
    float4 a0 = *(const float4*)(y + r0);
    float4 a1 = *(const float4*)(y + r1);
    float4 g0 = *(const float4*)(y + r0 + INTER);
    float4 g1 = *(const float4*)(y + r1 + INTER);
    float4 c1 = *(const float4*)(s1 + j);
    float4 c3 = *(const float4*)(s3 + j);
    ushort4 o;
    {
        float up = (a0.x + a1.x) * c1.x, gt = (g0.x + g1.x) * c3.x;
        o.x = f2bf_rne(gt * up / (1.f + __expf(-up)));
    }
    {
        float up = (a0.y + a1.y) * c1.y, gt = (g0.y + g1.y) * c3.y;
        o.y = f2bf_rne(gt * up / (1.f + __expf(-up)));
    }
    {
        float up = (a0.z + a1.z) * c1.z, gt = (g0.z + g1.z) * c3.z;
        o.z = f2bf_rne(gt * up / (1.f + __expf(-up)));
    }
    {
        float up = (a0.w + a1.w) * c1.w, gt = (g0.w + g1.w) * c3.w;
        o.w = f2bf_rne(gt * up / (1.f + __expf(-up)));
    }
    *(ushort4*)(h + (size_t)m * INTER + j) = o;
}

// ---------------- reduce 8 K-split partials, scale by w2_s ----------------
__global__ void reduce_k(const float* __restrict__ p,   // [8][MTOK][HIDDEN]
                         const float* __restrict__ s2, float* __restrict__ out)
{
    int i = (blockIdx.x * 256 + threadIdx.x) * 4;
    float4 acc = *(const float4*)(p + i);
#pragma unroll
    for (int s = 1; s < 8; ++s) {
        float4 v = *(const float4*)(p + (size_t)s * MTOK * HIDDEN + i);
        acc.x += v.x; acc.y += v.y; acc.z += v.z; acc.w += v.w;
    }
    int ncol = i & (HIDDEN - 1);
    float4 sc = *(const float4*)(s2 + ncol);
    acc.x *= sc.x; acc.y *= sc.y; acc.z *= sc.z; acc.w *= sc.w;
    *(float4*)(out + i) = acc;
}

extern "C" void kernel_launch(void* const* d_in, const int* in_sizes, int n_in,
                              void* d_out, int out_size, void* d_ws, size_t ws_size,
                              hipStream_t stream) {
    const float* x   = (const float*)d_in[0];
    const float* w1q = (const float*)d_in[1];
    const float* w1s = (const float*)d_in[2];
    const float* w3q = (const float*)d_in[3];
    const float* w3s = (const float*)d_in[4];
    const float* w2q = (const float*)d_in[5];
    const float* w2s = (const float*)d_in[6];
    float* out = (float*)d_out;

    char* ws = (char*)d_ws;
    unsigned short* xb = (unsigned short*)ws;                    // 1 MB  : x bf16 [128][4096]
    unsigned short* h  = (unsigned short*)(ws + (1u << 20));     // 2.75MB: h bf16 [128][11008]
    float* part        = (float*)(ws + (4u << 20));              // 22.5MB: gemm partials (reused)

    // 1) x -> bf16
    cvt_x_k<<<MTOK * HIDDEN / 4 / 256, 256, 0, stream>>>(x, xb);
    // 2) up/gate partials: merged N = [w1; w3], K-split 2
    gemm_part_k<<<dim3(NMERG / 64, 2), 128, 0, stream>>>(
        xb, w1q, w3q, INTER, part, HIDDEN, NMERG, HIDDEN / 2);
    // 3) SwiGLU -> h bf16
    swiglu_k<<<MTOK * INTER / 4 / 256, 256, 0, stream>>>(part, w1s, w3s, h);
    // 4) out partials: h @ w2^T, K-split 8
    gemm_part_k<<<dim3(HIDDEN / 64, 8), 128, 0, stream>>>(
        h, w2q, w2q, 1 << 30, part, INTER, HIDDEN, INTER / 8);
    // 5) reduce + scale
    reduce_k<<<MTOK * HIDDEN / 4 / 256, 256, 0, stream>>>(part, w2s, out);
}